// Round 5
// baseline (2223.185 us; speedup 1.0000x reference)
//
#include <hip/hip_runtime.h>
#include <stdint.h>

// Problem constants
#define B_SZ 2048
#define N_SZ 512
#define H_SZ 20
#define T_STEPS 3

typedef unsigned short u16;
typedef __attribute__((ext_vector_type(8))) short bf8;   // 8 bf16 (4 VGPRs)
typedef __attribute__((ext_vector_type(4))) float f4;    // MFMA 16x16 accumulator

#define MFMA(a, b, c) __builtin_amdgcn_mfma_f32_16x16x32_bf16((a), (b), (c), 0, 0, 0)

// HW RNE conversion: compiler emits v_cvt_pk_bf16_f32 for (pairs of) casts.
__device__ __forceinline__ u16 f2bf(float f) {
    __bf16 h = (__bf16)f;
    union { __bf16 b; u16 u; } v; v.b = h;
    return v.u;
}
__device__ __forceinline__ float bf2f(u16 h) {
    union { uint32_t u; float f; } v; v.u = ((uint32_t)h) << 16;
    return v.f;
}
__device__ __forceinline__ uint32_t pk2(float a, float b) {
    return (uint32_t)f2bf(a) | ((uint32_t)f2bf(b) << 16);
}
__device__ __forceinline__ uint2 pack4(f4 v) {
    uint2 r; r.x = pk2(v[0], v[1]); r.y = pk2(v[2], v[3]); return r;
}
// scratch2 addressing: [c (32 cols)][fblock^swizzle (8)][8], bf16 elements
__device__ __forceinline__ int scoff(int c, int f) {
    return c * 64 + (((f >> 3) ^ (c & 7)) << 3) + (f & 7);
}
__device__ __forceinline__ float sigm(float x) { return 1.f / (1.f + __expf(-x)); }

// ---------------- prep kernels ----------------

// Fused prep: x [B][N][H] f32 read ONCE per batch ->
//   nodes [B][nt(32)][h(20)][nl(16)] bf16 (tile-major, uint4 stores)
//   xo    [B][N][H] bf16 = x @ W_out[:,H:].T + b_out (uint2 stores)
__global__ __launch_bounds__(256)
void prep_fused(const float* __restrict__ x, const float* __restrict__ Wout,
                const float* __restrict__ bout,
                u16* __restrict__ nodes, u16* __restrict__ xo) {
    __shared__ float xt[N_SZ * H_SZ];      // 40960 B
    __shared__ float wo2[H_SZ * H_SZ];     // W_out[:, 20:40]
    __shared__ float bo[H_SZ];
    int tid = threadIdx.x;
    int b = blockIdx.x;
    const float4* xb4 = (const float4*)(x + (size_t)b * (N_SZ * H_SZ));
    #pragma unroll
    for (int i = 0; i < 10; i++) ((float4*)xt)[i * 256 + tid] = xb4[i * 256 + tid];
    for (int i = tid; i < H_SZ * H_SZ; i += 256)
        wo2[i] = Wout[(i / H_SZ) * 2 * H_SZ + H_SZ + (i % H_SZ)];
    if (tid < H_SZ) bo[tid] = bout[tid];
    __syncthreads();

    // nodes: 1280 uint4 groups; g = nt*40 + hp*2 + half, nl0 = half*8
    u16* nb = nodes + (size_t)b * (N_SZ * H_SZ);
    #pragma unroll
    for (int g0 = 0; g0 < 5; g0++) {
        int g = g0 * 256 + tid;
        int nt = g / 40, r = g - nt * 40;
        int hp = r >> 1, nl0 = (r & 1) * 8;
        union { uint4 v; u16 s[8]; } u;
        #pragma unroll
        for (int j = 0; j < 8; j++) u.s[j] = f2bf(xt[(nt * 16 + nl0 + j) * H_SZ + hp]);
        *(uint4*)&nb[(size_t)g * 8] = u.v;
    }

    // xo: one n per thread (x2), packed uint2 stores (40 B/row -> 8B aligned)
    u16* ob = xo + (size_t)b * (N_SZ * H_SZ);
    #pragma unroll
    for (int n0 = 0; n0 < 2; n0++) {
        int n = n0 * 256 + tid;
        float xl[H_SZ];
        #pragma unroll
        for (int h = 0; h < H_SZ; h++) xl[h] = xt[n * H_SZ + h];
        #pragma unroll
        for (int q = 0; q < 5; q++) {
            float s[4];
            #pragma unroll
            for (int k = 0; k < 4; k++) {
                int hp = q * 4 + k;
                float acc = bo[hp];
                #pragma unroll
                for (int h = 0; h < H_SZ; h++) acc += xl[h] * wo2[hp * H_SZ + h];
                s[k] = acc;
            }
            uint2 v; v.x = pk2(s[0], s[1]); v.y = pk2(s[2], s[3]);
            *(uint2*)&ob[(size_t)n * H_SZ + q * 4] = v;
        }
    }
}

// A fragment tables: pAT[nt][kt][lane][8] = A[n][m] (B-op for agg_in),
//                    pA [nt][kt][lane][8] = A[m][n] (B-op for agg_out)
__global__ void prep_afrag(const float* __restrict__ A, u16* __restrict__ pAT,
                           u16* __restrict__ pA) {
    int idx = blockIdx.x * 256 + threadIdx.x;    // (nt*16 + kt)*64 + lane
    int lane = idx & 63;
    int kt = (idx >> 6) & 15;
    int nt = idx >> 10;
    int n = nt * 16 + (lane & 15);
    int k0 = kt * 32 + (lane >> 4) * 8;
    u16* d1 = pAT + (size_t)idx * 8;
    u16* d2 = pA + (size_t)idx * 8;
    #pragma unroll
    for (int j = 0; j < 8; j++) {
        int m = k0 + j;
        d1[j] = f2bf(A[(size_t)n * N_SZ + m]);
        d2[j] = f2bf(A[(size_t)m * N_SZ + n]);
    }
}

// Gate weight fragment tables.
// wbig: M=96 (rows 0-19 z | 32-51 r | 64-83 h-av; zero pad), K=64
//       (k 0-39: W*w over [agg_in,agg_out]; k 40-59: W*u over fn (zero for h); 60-63 zero)
// whu : M=32 K=32 : W5u zero-padded
// wo1 : M=32 K=32 : W_out[:, :H] zero-padded
__global__ void prep_wfrag(const float* __restrict__ W3w, const float* __restrict__ W3u,
                           const float* __restrict__ W4w, const float* __restrict__ W4u,
                           const float* __restrict__ W5w, const float* __restrict__ W5u,
                           const float* __restrict__ Wout,
                           u16* __restrict__ wbig, u16* __restrict__ whu, u16* __restrict__ wo1) {
    int t = blockIdx.x * 256 + threadIdx.x;      // 0..1023
    int lane = t & 63;
    int l16 = lane & 15, quad = lane >> 4;
    if (t < 768) {
        int kt = (t >> 6) & 1;
        int mt = t >> 7;
        int mrow = mt * 16 + l16;
        int g = mrow >> 5, lr = mrow & 31;
        u16* d = wbig + (size_t)t * 8;
        #pragma unroll
        for (int j = 0; j < 8; j++) {
            int k = kt * 32 + quad * 8 + j;
            float v = 0.f;
            if (lr < 20) {
                if (k < 40) {
                    const float* W = (g == 0) ? W3w : (g == 1) ? W4w : W5w;
                    v = W[lr * 40 + k];
                } else if (k < 60 && g < 2) {
                    const float* U = (g == 0) ? W3u : W4u;
                    v = U[lr * 20 + (k - 40)];
                }
            }
            d[j] = f2bf(v);
        }
    } else if (t < 896) {
        int tt = t - 768;
        int mrow = (tt >> 6) * 16 + l16;
        u16* d = whu + (size_t)tt * 8;
        #pragma unroll
        for (int j = 0; j < 8; j++) {
            int k = quad * 8 + j;
            d[j] = f2bf((mrow < 20 && k < 20) ? W5u[mrow * 20 + k] : 0.f);
        }
    } else {
        int tt = t - 896;
        int mrow = (tt >> 6) * 16 + l16;
        u16* d = wo1 + (size_t)tt * 8;
        #pragma unroll
        for (int j = 0; j < 8; j++) {
            int k = quad * 8 + j;
            d[j] = f2bf((mrow < 20 && k < 20) ? Wout[mrow * 40 + k] : 0.f);
        }
    }
}

__global__ void ws_too_small(float* out) { out[0] = 12345.0f; }

// ---------------- fused all-steps kernel ----------------
// One workgroup = 2 batches for ALL T steps. fn state is carried in LDS (Xs)
// across steps: fn_new is held in registers during the p-loop (p statically
// unrolled so sv[][][] stays in VGPRs) and written back to Xs at the step
// boundary between two barriers. nodes global is READ once (initial stage)
// and never written -> no global round-trip between steps.
__global__ __launch_bounds__(256, 2)
void step_kernel(const u16* __restrict__ pAT, const u16* __restrict__ pA,
                 const u16* __restrict__ wbig, const u16* __restrict__ whu,
                 const u16* __restrict__ wo1, const u16* __restrict__ xo,
                 const u16* __restrict__ nodes, float* __restrict__ out)
{
    __shared__ __align__(16) u16 lds_all[40 * 512 + 4 * 2048];   // Xs | sc2, 57344 B
    u16* Xs = lds_all;
    int tid = threadIdx.x;
    int wv = tid >> 6, lane = tid & 63;
    int l16 = lane & 15, quad = lane >> 4;
    int b0 = blockIdx.x * 2;
    u16* scw = lds_all + 40 * 512 + wv * 2048;

    // ---- initial stage: nodes[b0..b0+1] -> Xs (swizzled), once ----
    {
        const u16* nb = nodes + (size_t)b0 * (N_SZ * H_SZ);   // tile-major
        #pragma unroll
        for (int i = 0; i < 10; i++) {
            int idx = i * 256 + tid;                 // 0..2559 uint4-groups
            uint4 v = *(const uint4*)(nb + (size_t)idx * 8);
            int bs = idx >= 1280 ? 1 : 0;
            int idxb = idx - bs * 1280;
            int nt = idxb / 40;                      // 40 groups per n-tile
            int r  = idxb - nt * 40;
            int hp = r >> 1;
            int half = r & 1;                        // nl0 = half*8
            int row = bs * 20 + hp;
            int mb = nt * 2 + half;                  // (nt*16+nl0)>>3
            *(uint4*)&Xs[row * 512 + ((mb ^ (row & 7)) << 3)] = v;
        }
    }
    __syncthreads();

    #pragma unroll 1
    for (int t = 0; t < T_STEPS; t++) {
        // fn_new carry: [p][ntL][ct]; quad-rows in sv, rows 16..19 (quad0) in sv2.
        // p/ntL/ct all statically unrolled -> pure VGPR (no scratch).
        uint2 sv[4][2][2];
        uint2 sv2[4][2][2];

        #pragma unroll
        for (int p = 0; p < 4; p++) {
            int nt0 = wv * 8 + p * 2;

            // ---- phase 2: aggregation GEMM for an n-tile pair ----
            f4 acc[2][3][2];                    // [ntL][mt][agg]
            #pragma unroll
            for (int a0 = 0; a0 < 2; a0++)
                #pragma unroll
                for (int a1 = 0; a1 < 3; a1++)
                    #pragma unroll
                    for (int a2 = 0; a2 < 2; a2++)
                        acc[a0][a1][a2] = (f4){0.f, 0.f, 0.f, 0.f};

            for (int kt = 0; kt < 16; kt++) {
                bf8 af[3];
                #pragma unroll
                for (int mt = 0; mt < 3; mt++) {
                    int row = mt * 16 + l16;                   // rows 40-47 read junk; C rows ignored
                    int kb = (kt * 4 + quad) ^ (row & 7);
                    af[mt] = *(const bf8*)&Xs[row * 512 + kb * 8];
                }
                #pragma unroll
                for (int ntL = 0; ntL < 2; ntL++) {
                    uint32_t fo = ((uint32_t)((nt0 + ntL) * 16 + kt) * 64 + (uint32_t)lane) * 8;
                    bf8 bi = *(const bf8*)(pAT + fo);
                    bf8 bo = *(const bf8*)(pA + fo);
                    #pragma unroll
                    for (int mt = 0; mt < 3; mt++) {
                        acc[ntL][mt][0] = MFMA(af[mt], bi, acc[ntL][mt][0]);
                        acc[ntL][mt][1] = MFMA(af[mt], bo, acc[ntL][mt][1]);
                    }
                }
            }

            // ---- phase 3: gates + update + output, per n-tile ----
            #pragma unroll
            for (int ntL = 0; ntL < 2; ntL++) {
                int nt = nt0 + ntL;
                int nglob = nt * 16 + l16;

                // 3a: agg C-tiles -> scratch feats 0..39, packed uint2
                #pragma unroll
                for (int mt = 0; mt < 3; mt++) {
                    if (mt < 2 || quad < 2) {
                        int row0 = mt * 16 + quad * 4;          // 4-aligned; 20-boundary safe
                        int bs = (row0 >= 20) ? 1 : 0;
                        int h0 = row0 - bs * 20;
                        int c = bs * 16 + l16;
                        *(uint2*)&scw[scoff(c, h0)]      = pack4(acc[ntL][mt][0]);
                        *(uint2*)&scw[scoff(c, 20 + h0)] = pack4(acc[ntL][mt][1]);
                    }
                }
                // 3a2: fn -> feats 40..59 (packed writes); zero feats 60..63
                {
                    int c = lane & 31;
                    int h0 = (lane >> 5) * 10;
                    int bs = c >> 4, nl = c & 15;
                    int m = nt * 16 + nl;
                    int mb = m >> 3, mo = m & 7;
                    u16 fnv[10];
                    #pragma unroll
                    for (int i = 0; i < 10; i++) {
                        int row = bs * 20 + h0 + i;
                        fnv[i] = Xs[row * 512 + ((mb ^ (row & 7)) << 3) + mo];
                    }
                    if (h0 == 0) {          // feats 40..49
                        uint2 a; a.x = fnv[0] | (fnv[1] << 16); a.y = fnv[2] | (fnv[3] << 16);
                        *(uint2*)&scw[scoff(c, 40)] = a;
                        uint2 b2; b2.x = fnv[4] | (fnv[5] << 16); b2.y = fnv[6] | (fnv[7] << 16);
                        *(uint2*)&scw[scoff(c, 44)] = b2;
                        *(uint32_t*)&scw[scoff(c, 48)] = (uint32_t)fnv[8] | ((uint32_t)fnv[9] << 16);
                    } else {                // feats 50..59 + zero 60..63
                        *(uint32_t*)&scw[scoff(c, 50)] = (uint32_t)fnv[0] | ((uint32_t)fnv[1] << 16);
                        uint2 a; a.x = fnv[2] | (fnv[3] << 16); a.y = fnv[4] | (fnv[5] << 16);
                        *(uint2*)&scw[scoff(c, 52)] = a;
                        uint2 b2; b2.x = fnv[6] | (fnv[7] << 16); b2.y = fnv[8] | (fnv[9] << 16);
                        *(uint2*)&scw[scoff(c, 56)] = b2;
                        uint2 z; z.x = 0u; z.y = 0u;
                        *(uint2*)&scw[scoff(c, 60)] = z;
                    }
                }

                // 3b: G1 = Wbig(96x64) @ scratch2(64x32): z|r|h_av pre-activations
                f4 g1[6][2];
                #pragma unroll
                for (int a0 = 0; a0 < 6; a0++) { g1[a0][0] = (f4){0,0,0,0}; g1[a0][1] = (f4){0,0,0,0}; }
                #pragma unroll
                for (int kt = 0; kt < 2; kt++) {
                    bf8 bfr[2];
                    #pragma unroll
                    for (int ct = 0; ct < 2; ct++) {
                        int c = ct * 16 + l16;
                        int fb = (kt * 4 + quad) ^ (c & 7);
                        bfr[ct] = *(const bf8*)&scw[c * 64 + fb * 8];
                    }
                    #pragma unroll
                    for (int mt = 0; mt < 6; mt++) {
                        bf8 wf = *(const bf8*)(wbig + ((uint32_t)(mt * 2 + kt) * 64 + (uint32_t)lane) * 8);
                        g1[mt][0] = MFMA(wf, bfr[0], g1[mt][0]);
                        g1[mt][1] = MFMA(wf, bfr[1], g1[mt][1]);
                    }
                }

                // 3c: rp = sigmoid(r)*fn -> feats 0..19 (packed); keep fn in regs
                float fnr[2][4], fnr2[2][4];
                #pragma unroll
                for (int ct = 0; ct < 2; ct++) {
                    int c = ct * 16 + l16;
                    uint2 fl = *(const uint2*)&scw[scoff(c, 40 + quad * 4)];
                    fnr[ct][0] = bf2f((u16)fl.x);  fnr[ct][1] = bf2f((u16)(fl.x >> 16));
                    fnr[ct][2] = bf2f((u16)fl.y);  fnr[ct][3] = bf2f((u16)(fl.y >> 16));
                    uint2 rp;
                    rp.x = pk2(sigm(g1[2][ct][0]) * fnr[ct][0], sigm(g1[2][ct][1]) * fnr[ct][1]);
                    rp.y = pk2(sigm(g1[2][ct][2]) * fnr[ct][2], sigm(g1[2][ct][3]) * fnr[ct][3]);
                    *(uint2*)&scw[scoff(c, quad * 4)] = rp;
                    if (quad == 0) {
                        uint2 fl2 = *(const uint2*)&scw[scoff(c, 56)];
                        fnr2[ct][0] = bf2f((u16)fl2.x);  fnr2[ct][1] = bf2f((u16)(fl2.x >> 16));
                        fnr2[ct][2] = bf2f((u16)fl2.y);  fnr2[ct][3] = bf2f((u16)(fl2.y >> 16));
                        uint2 rp2;
                        rp2.x = pk2(sigm(g1[3][ct][0]) * fnr2[ct][0], sigm(g1[3][ct][1]) * fnr2[ct][1]);
                        rp2.y = pk2(sigm(g1[3][ct][2]) * fnr2[ct][2], sigm(g1[3][ct][3]) * fnr2[ct][3]);
                        *(uint2*)&scw[scoff(c, 16)] = rp2;
                    }
                }

                // 3d: hu = W5u_pad(32x32) @ rp
                f4 hu[2][2];
                hu[0][0] = (f4){0,0,0,0}; hu[0][1] = (f4){0,0,0,0};
                hu[1][0] = (f4){0,0,0,0}; hu[1][1] = (f4){0,0,0,0};
                #pragma unroll
                for (int ct = 0; ct < 2; ct++) {
                    int c = ct * 16 + l16;
                    int fb = quad ^ (c & 7);
                    bf8 bfr = *(const bf8*)&scw[c * 64 + fb * 8];
                    #pragma unroll
                    for (int mt = 0; mt < 2; mt++) {
                        bf8 wf = *(const bf8*)(whu + ((uint32_t)(mt * 64) + (uint32_t)lane) * 8);
                        hu[mt][ct] = MFMA(wf, bfr, hu[mt][ct]);
                    }
                }

                // 3e: fn_new = (1-z)*fn + z*tanh(h_av + hu); packed scw write;
                //     carry packed fn_new in registers (written to Xs at step boundary)
                #pragma unroll
                for (int ct = 0; ct < 2; ct++) {
                    int c = ct * 16 + l16;
                    float w4[4];
                    #pragma unroll
                    for (int r = 0; r < 4; r++) {
                        float z = sigm(g1[0][ct][r]);
                        float hpre = g1[4][ct][r] + hu[0][ct][r];
                        float hv = 2.f / (1.f + __expf(-2.f * hpre)) - 1.f;
                        w4[r] = (1.f - z) * fnr[ct][r] + z * hv;
                    }
                    uint2 wp; wp.x = pk2(w4[0], w4[1]); wp.y = pk2(w4[2], w4[3]);
                    *(uint2*)&scw[scoff(c, quad * 4)] = wp;
                    sv[p][ntL][ct] = wp;
                    if (quad == 0) {
                        float w42[4];
                        #pragma unroll
                        for (int r = 0; r < 4; r++) {
                            float z = sigm(g1[1][ct][r]);
                            float hpre = g1[5][ct][r] + hu[1][ct][r];
                            float hv = 2.f / (1.f + __expf(-2.f * hpre)) - 1.f;
                            w42[r] = (1.f - z) * fnr2[ct][r] + z * hv;
                        }
                        uint2 wp2; wp2.x = pk2(w42[0], w42[1]); wp2.y = pk2(w42[2], w42[3]);
                        *(uint2*)&scw[scoff(c, 16)] = wp2;
                        sv2[p][ntL][ct] = wp2;
                    }
                }

                // 3f: og = Wo1_pad(32x32) @ fn_new
                f4 og[2][2];
                og[0][0] = (f4){0,0,0,0}; og[0][1] = (f4){0,0,0,0};
                og[1][0] = (f4){0,0,0,0}; og[1][1] = (f4){0,0,0,0};
                #pragma unroll
                for (int ct = 0; ct < 2; ct++) {
                    int c = ct * 16 + l16;
                    int fb = quad ^ (c & 7);
                    bf8 bfr = *(const bf8*)&scw[c * 64 + fb * 8];
                    #pragma unroll
                    for (int mt = 0; mt < 2; mt++) {
                        bf8 wf = *(const bf8*)(wo1 + ((uint32_t)(mt * 64) + (uint32_t)lane) * 8);
                        og[mt][ct] = MFMA(wf, bfr, og[mt][ct]);
                    }
                }

                // 3g: out = og + xo, float4 stores
                #pragma unroll
                for (int ct = 0; ct < 2; ct++) {
                    int bg = b0 + ct;
                    size_t xob = ((size_t)bg * N_SZ + nglob) * H_SZ;
                    size_t ob = (((size_t)t * B_SZ + bg) * N_SZ + nglob) * H_SZ;
                    {
                        uint2 xp = *(const uint2*)(xo + xob + quad * 4);
                        f4 v;
                        v[0] = og[0][ct][0] + bf2f((u16)xp.x);
                        v[1] = og[0][ct][1] + bf2f((u16)(xp.x >> 16));
                        v[2] = og[0][ct][2] + bf2f((u16)xp.y);
                        v[3] = og[0][ct][3] + bf2f((u16)(xp.y >> 16));
                        *(f4*)(out + ob + quad * 4) = v;
                    }
                    if (quad == 0) {
                        uint2 xp = *(const uint2*)(xo + xob + 16);
                        f4 v;
                        v[0] = og[1][ct][0] + bf2f((u16)xp.x);
                        v[1] = og[1][ct][1] + bf2f((u16)(xp.x >> 16));
                        v[2] = og[1][ct][2] + bf2f((u16)xp.y);
                        v[3] = og[1][ct][3] + bf2f((u16)(xp.y >> 16));
                        *(f4*)(out + ob + 16) = v;
                    }
                }
            }
        }

        // ---- step boundary: write carried fn_new into Xs (no global round-trip) ----
        if (t < T_STEPS - 1) {
            __syncthreads();   // all waves done reading step-t Xs
            #pragma unroll
            for (int p = 0; p < 4; p++) {
                #pragma unroll
                for (int ntL = 0; ntL < 2; ntL++) {
                    int nt = wv * 8 + p * 2 + ntL;
                    int m = nt * 16 + l16, mb = m >> 3, mo = m & 7;
                    #pragma unroll
                    for (int ct = 0; ct < 2; ct++) {
                        uint2 wp = sv[p][ntL][ct];
                        #pragma unroll
                        for (int r = 0; r < 4; r++) {
                            int row = ct * 20 + quad * 4 + r;
                            u16 w = (u16)((r & 1) ? ((r & 2) ? (wp.y >> 16) : (wp.x >> 16))
                                                  : ((r & 2) ? wp.y : wp.x));
                            Xs[row * 512 + ((mb ^ (row & 7)) << 3) + mo] = w;
                        }
                        if (quad == 0) {
                            uint2 wp2 = sv2[p][ntL][ct];
                            #pragma unroll
                            for (int r = 0; r < 4; r++) {
                                int row = ct * 20 + 16 + r;
                                u16 w = (u16)((r & 1) ? ((r & 2) ? (wp2.y >> 16) : (wp2.x >> 16))
                                                      : ((r & 2) ? wp2.y : wp2.x));
                                Xs[row * 512 + ((mb ^ (row & 7)) << 3) + mo] = w;
                            }
                        }
                    }
                }
            }
            __syncthreads();   // Xs now holds step-(t+1) input
        }
    }
}

// ---------------- host ----------------
#define WS_NODES   0
#define WS_XO      41943040UL
#define WS_PAT     83886080UL
#define WS_PA      84410368UL
#define WS_WBIG    84934656UL
#define WS_WHU     84946944UL
#define WS_WO1     84948992UL
#define WS_NEEDED  84951040UL

extern "C" void kernel_launch(void* const* d_in, const int* in_sizes, int n_in,
                              void* d_out, int out_size, void* d_ws, size_t ws_size,
                              hipStream_t stream) {
    const float* x    = (const float*)d_in[0];
    const float* A    = (const float*)d_in[1];
    const float* W3w  = (const float*)d_in[2];
    const float* W3u  = (const float*)d_in[3];
    const float* W4w  = (const float*)d_in[4];
    const float* W4u  = (const float*)d_in[5];
    const float* W5w  = (const float*)d_in[6];
    const float* W5u  = (const float*)d_in[7];
    const float* Wout = (const float*)d_in[8];
    const float* bout = (const float*)d_in[9];
    float* out = (float*)d_out;

    if (ws_size < WS_NEEDED) {           // unambiguous failure signature
        ws_too_small<<<1, 1, 0, stream>>>(out);
        return;
    }
    char* ws = (char*)d_ws;
    u16* nodes = (u16*)(ws + WS_NODES);
    u16* xo    = (u16*)(ws + WS_XO);
    u16* pAT   = (u16*)(ws + WS_PAT);
    u16* pA    = (u16*)(ws + WS_PA);
    u16* wbig  = (u16*)(ws + WS_WBIG);
    u16* whu   = (u16*)(ws + WS_WHU);
    u16* wo1   = (u16*)(ws + WS_WO1);

    prep_fused<<<B_SZ, 256, 0, stream>>>(x, Wout, bout, nodes, xo);
    prep_afrag<<<128, 256, 0, stream>>>(A, pAT, pA);
    prep_wfrag<<<4, 256, 0, stream>>>(W3w, W3u, W4w, W4u, W5w, W5u, Wout, wbig, whu, wo1);

    step_kernel<<<B_SZ / 2, 256, 0, stream>>>(pAT, pA, wbig, whu, wo1, xo, nodes, out);
}